// Round 7
// baseline (250.516 us; speedup 1.0000x reference)
//
#include <hip/hip_runtime.h>

// out[b, n] = sum_k x[b,k] * w[n,k]
// B=8, S=1, K=4096, N=11008, fp32.
//
// Round-6 post-mortem: nt-bit was null (-1.5%). Five theories down; all six
// prior variants share ONE path: weight bytes return through VGPR loads
// (L1-allocating global_load_dwordx4). A per-CU outstanding-line-miss cap
// (~64 x 64B / ~375ns) predicts ~2.7 TB/s device-wide -- exactly our
// 2.4-2.6 TB/s plateau. This round switches the weight (and x) stream to
// __builtin_amdgcn_global_load_lds (async DMA direct to LDS, no VGPR/L1
// return) -- the one read machinery not yet tried, and the guide's biggest
// single GEMM lever. Structure: T3-minimum 2-phase, double-buffered LDS
// (w: 8 rows x 2KB, x: 8 batches x 2KB, x2 buffers = 64 KB -> 2 blocks/CU),
// one barrier per chunk, 8 chunks.

#define BATCH 8
#define KDIM 4096
#define K4 (KDIM / 4)          // 1024 float4 per row
#define NDIM 11008
#define CK4 128                // float4 per row per chunk (2 KB)
#define NCHUNK (K4 / CK4)      // 8
#define BLOCK 256              // 4 waves
#define ROWS_PER_BLOCK 8       // 4 waves * 2 rows; 1376 blocks exact

__device__ __forceinline__ void gld_lds16(const float4* g, float4* l) {
    // 16-byte async global->LDS DMA. LDS dest must be wave-uniform + lane*16
    // (verified below: dest col = (wave&1)*64 + lane within each 128-col row).
    __builtin_amdgcn_global_load_lds(
        (const __attribute__((address_space(1))) void*)g,
        (__attribute__((address_space(3))) void*)l,
        16, 0, 0);
}

__global__ __launch_bounds__(BLOCK)
void ActivationSparseLinear_4982162063725_kernel(const float* __restrict__ x,
                                                 const float* __restrict__ w,
                                                 float* __restrict__ out) {
    __shared__ float4 wsm[2][ROWS_PER_BLOCK][CK4];  // 2 x 16 KB weights
    __shared__ float4 xsm[2][BATCH][CK4];           // 2 x 16 KB activations

    const int tid   = threadIdx.x;
    const int lane  = tid & 63;
    const int wave  = tid >> 6;
    const int nbase = blockIdx.x * ROWS_PER_BLOCK;

    const float4* xg4 = (const float4*)x;   // [BATCH][K4]
    const float4* wg4 = (const float4*)w;   // [NDIM][K4]

    const int sub = tid >> 7;               // 0/1: which row of each pair
    const int col = tid & 127;              // float4 column within the 2 KB row

    float acc[2][BATCH];
#pragma unroll
    for (int r = 0; r < 2; ++r)
#pragma unroll
        for (int b = 0; b < BATCH; ++b) acc[r][b] = 0.0f;

    // Stage chunk c into buffer bf: 8 DMA issues/thread, 32 KB/block,
    // all contiguous 2 KB segments (row-major weight rows, per-batch x rows).
    auto stage = [&](int bf, int c) {
#pragma unroll
        for (int j = 0; j < 4; ++j) {
            const int row = j * 2 + sub;
            gld_lds16(wg4 + (size_t)(nbase + row) * K4 + c * CK4 + col,
                      &wsm[bf][row][col]);
        }
#pragma unroll
        for (int j = 0; j < 4; ++j) {
            const int b = j * 2 + sub;
            gld_lds16(xg4 + (size_t)b * K4 + c * CK4 + col,
                      &xsm[bf][b][col]);
        }
    };

    stage(0, 0);
    __syncthreads();                        // drains vmcnt(0): chunk 0 landed

    int bf = 0;
    for (int c = 0; c < NCHUNK; ++c) {
        if (c + 1 < NCHUNK) stage(bf ^ 1, c + 1);   // DMA next chunk in flight

        // Compute current chunk from LDS: pure ds_read_b128 + fmac, no vmcnt.
        const int r0 = 2 * wave, r1 = 2 * wave + 1;
#pragma unroll
        for (int i = 0; i < CK4 / 64; ++i) {        // 2 sub-steps
            const int kk = i * 64 + lane;
            const float4 w0 = wsm[bf][r0][kk];      // conflict-free b128
            const float4 w1 = wsm[bf][r1][kk];
            float4 xv[BATCH];
#pragma unroll
            for (int b = 0; b < BATCH; ++b) xv[b] = xsm[bf][b][kk];
#pragma unroll
            for (int b = 0; b < BATCH; ++b) {
                acc[0][b] += w0.x * xv[b].x + w0.y * xv[b].y
                           + w0.z * xv[b].z + w0.w * xv[b].w;
                acc[1][b] += w1.x * xv[b].x + w1.y * xv[b].y
                           + w1.z * xv[b].z + w1.w * xv[b].w;
            }
        }
        __syncthreads();                    // next-chunk DMA done; readers done
        bf ^= 1;
    }

    // Butterfly-reduce each accumulator across the 64-lane wave.
#pragma unroll
    for (int r = 0; r < 2; ++r)
#pragma unroll
        for (int b = 0; b < BATCH; ++b) {
            float v = acc[r][b];
#pragma unroll
            for (int off = 32; off > 0; off >>= 1)
                v += __shfl_xor(v, off, 64);
            acc[r][b] = v;
        }

    if (lane == 0) {
#pragma unroll
        for (int r = 0; r < 2; ++r)
#pragma unroll
            for (int b = 0; b < BATCH; ++b)
                out[(size_t)b * NDIM + nbase + 2 * wave + r] = acc[r][b];
    }
}

extern "C" void kernel_launch(void* const* d_in, const int* in_sizes, int n_in,
                              void* d_out, int out_size, void* d_ws, size_t ws_size,
                              hipStream_t stream) {
    const float* x = (const float*)d_in[0];   // (8, 1, 4096) fp32
    const float* w = (const float*)d_in[1];   // (11008, 4096) fp32
    float* out = (float*)d_out;               // (8, 1, 11008) fp32

    dim3 grid(NDIM / ROWS_PER_BLOCK);         // 1376 blocks, exact fit
    ActivationSparseLinear_4982162063725_kernel<<<grid, BLOCK, 0, stream>>>(x, w, out);
}